// Round 6
// baseline (139.111 us; speedup 1.0000x reference)
//
#include <hip/hip_runtime.h>

#define HID 64
#define NTOK 66          // VOCAB_SIZE + 2
#define SEQ 64
#define WIN0 55          // SEQ_LEN - 1 - MEMORY_SLOTS
#define NW 8
#define LDS_STRIDE 72    // ushorts per table row (144B; token -> bank-quad is uniform)
#define ITERS 8          // iterations per block (rows/block = 512)
#define ROWS_PER_ITER 64 // 4 waves x 16 rows

typedef short short8 __attribute__((ext_vector_type(8)));
typedef unsigned short ushort8v __attribute__((ext_vector_type(8)));
typedef unsigned int uint4v __attribute__((ext_vector_type(4)));
typedef float float2v __attribute__((ext_vector_type(2)));
typedef float float4v __attribute__((ext_vector_type(4)));

static __device__ __forceinline__ unsigned short f2bf(float f) {
    union { float f; unsigned u; } v; v.f = f;
    unsigned r = v.u + 0x7FFFu + ((v.u >> 16) & 1u);
    return (unsigned short)(r >> 16);
}
static __device__ __forceinline__ float u2f(unsigned u) {
    union { unsigned u; float f; } v; v.u = u;
    return v.f;
}

// Kernel 1: tables T1[t][n] = b1[n] + sum_k emb[t][k]*W1[n][k]
//           T2[t][n] = 0.125 * sum_k emb[t][k]*W1[n][64+k]
// stored bf16 in ws: [2][66][64]
__global__ void build_tables(const float* __restrict__ embed,
                             const float* __restrict__ W1,
                             const float* __restrict__ b1,
                             unsigned short* __restrict__ tbl) {
    int b = blockIdx.x;      // 0..131
    int tb = b & 1;
    int t  = b >> 1;
    int n  = threadIdx.x;    // 0..63
    float acc = tb ? 0.0f : b1[n];
    const float* er = embed + t * HID;
    const float* wr = W1 + n * (2 * HID) + tb * HID;
#pragma unroll 8
    for (int k = 0; k < HID; ++k) acc += er[k] * wr[k];
    if (tb) acc *= 0.125f;
    tbl[tb * (NTOK * HID) + t * HID + n] = f2bf(acc);
}

// Kernel 2: logits^T = W2 (A-op) x h^T (B-op) via mfma_f32_16x16x32_bf16.
// Chunk-level software pipeline: LDS reads for the NEXT chunk are issued
// (into named stage arrays gA_/gB_) before the CURRENT chunk's VALU sum
// consumes its registers -> LDS latency hides under the add tree.
__global__ __launch_bounds__(256, 4) void fused_forward(
    const int* __restrict__ seqs,
    const int* __restrict__ qtok,
    const float* __restrict__ W2,
    const float* __restrict__ b2,
    const unsigned short* __restrict__ tbl,
    float* __restrict__ out)
{
    __shared__ unsigned short T_lds[2 * NTOK * LDS_STRIDE]; // 19008 B

    int tid  = threadIdx.x;
    int wv   = tid >> 6;
    int l    = tid & 63;
    int lrow = l & 15;          // W2 row within n-tile / batch row within tile
    int lg   = l >> 4;
    int lk8  = lg * 8;          // k offset within 32-wide K chunk

    int row0 = blockIdx.x * (ITERS * ROWS_PER_ITER) + wv * 16 + lrow;

// scalar token loads (proven-clean HBM traffic)
#define LOADT(s, t_) { \
    int row_ = row0 + (t_) * ROWS_PER_ITER; \
    q##s = qtok[row_]; \
    const int* sp_ = seqs + row_ * SEQ + WIN0; \
    _Pragma("unroll") \
    for (int j = 0; j < NW; ++j) w##s[j] = sp_[j]; \
}

// issue 8 ds_read_b128 for the window rows of one chunk
#define GATHER8(g, ww, k0c) { \
    _Pragma("unroll") \
    for (int j = 0; j < NW; ++j) \
        (g)[j] = *(const uint4v*)(T_lds + NTOK * LDS_STRIDE + (ww)[j] * LDS_STRIDE + (k0c)); \
}

// sum 8 prefetched rows + T1 row (read here, added LAST so its latency
// hides under the add tree), relu, pack to bf16 short8
#define SUMCVT(aout, g, qq, k0c) { \
    uint4v t1_ = *(const uint4v*)(T_lds + (qq) * LDS_STRIDE + (k0c)); \
    float2v acc_[4]; \
    _Pragma("unroll") \
    for (int i = 0; i < 4; ++i) { \
        acc_[i].x = u2f((g)[0][i] << 16); acc_[i].y = u2f((g)[0][i] & 0xFFFF0000u); } \
    _Pragma("unroll") \
    for (int j = 1; j < NW; ++j) { \
        _Pragma("unroll") \
        for (int i = 0; i < 4; ++i) { \
            float2v p_; p_.x = u2f((g)[j][i] << 16); p_.y = u2f((g)[j][i] & 0xFFFF0000u); \
            acc_[i] += p_; } } \
    _Pragma("unroll") \
    for (int i = 0; i < 4; ++i) { \
        float2v p_; p_.x = u2f(t1_[i] << 16); p_.y = u2f(t1_[i] & 0xFFFF0000u); \
        acc_[i] += p_; } \
    _Pragma("unroll") \
    for (int i = 0; i < 4; ++i) { \
        (aout)[2*i]   = (short)f2bf(fmaxf(acc_[i].x, 0.0f)); \
        (aout)[2*i+1] = (short)f2bf(fmaxf(acc_[i].y, 0.0f)); } \
}

// MFMA (bias folded into C-operand init) + dwordx4 stores
#define MFST(t_, A0, A1) { \
    float* op = out + (size_t)(row0 + (t_) * ROWS_PER_ITER) * HID; \
    _Pragma("unroll") \
    for (int nt = 0; nt < 4; ++nt) { \
        float4v acc = b2v[nt]; \
        acc = __builtin_amdgcn_mfma_f32_16x16x32_bf16(wfrag[nt][0], A0, acc, 0, 0, 0); \
        acc = __builtin_amdgcn_mfma_f32_16x16x32_bf16(wfrag[nt][1], A1, acc, 0, 0, 0); \
        *(float4v*)(op + nt * 16 + lg * 4) = acc; } \
}

// one pipelined iteration: cur tokens C, next tokens N
#define ITER_FULL(C, N, t_) { \
    int qc_ = q##C; \
    GATHER8(gB_, w##C, 32 + lk8);      /* c1 reads fly          */ \
    SUMCVT(a0, gA_, qc_, lk8);         /* consume c0, cover c1  */ \
    LOADT(C, (t_) + 2);                /* tokens for t+2        */ \
    GATHER8(gA_, w##N, lk8);           /* next iter c0 reads    */ \
    SUMCVT(a1, gB_, qc_, 32 + lk8);    /* consume c1, cover c0' */ \
    MFST(t_, a0, a1); \
}
#define ITER_NOLOAD(C, N, t_) { \
    int qc_ = q##C; \
    GATHER8(gB_, w##C, 32 + lk8); \
    SUMCVT(a0, gA_, qc_, lk8); \
    GATHER8(gA_, w##N, lk8); \
    SUMCVT(a1, gB_, qc_, 32 + lk8); \
    MFST(t_, a0, a1); \
}
#define ITER_LAST(C, t_) { \
    int qc_ = q##C; \
    GATHER8(gB_, w##C, 32 + lk8); \
    SUMCVT(a0, gA_, qc_, lk8); \
    SUMCVT(a1, gB_, qc_, 32 + lk8); \
    MFST(t_, a0, a1); \
}

    int qA, qB;
    int wA[NW], wB[NW];

    // ---- (1) iter 0/1 token loads: HBM latency hides under W2+fill+barrier ----
    LOADT(A, 0);
    LOADT(B, 1);

    // ---- (2) W2 A-fragments in registers (whole 64x64) + b2 float4 ----
    short8  wfrag[4][2];
    float4v b2v[4];
#pragma unroll
    for (int nt = 0; nt < 4; ++nt) {
        b2v[nt] = *(const float4v*)(b2 + nt * 16 + lg * 4);
#pragma unroll
        for (int kc = 0; kc < 2; ++kc) {
            const float* wp = W2 + (nt * 16 + lrow) * HID + kc * 32 + lk8;
            short8 f;
#pragma unroll
            for (int j = 0; j < 8; ++j) f[j] = (short)f2bf(wp[j]);
            wfrag[nt][kc] = f;
        }
    }

    // ---- (3) fill LDS tables (16B chunks; row stride 144B) ----
    for (int i = tid; i < 2 * NTOK * (HID / 8); i += 256) {
        int tbi = i / (NTOK * 8);
        int rem = i - tbi * (NTOK * 8);
        int t   = rem >> 3;
        int kq  = (rem & 7) << 3;
        *(ushort8v*)(T_lds + tbi * (NTOK * LDS_STRIDE) + t * LDS_STRIDE + kq) =
            *(const ushort8v*)(tbl + tbi * (NTOK * HID) + t * HID + kq);
    }
    __syncthreads();

    // ---- (4) chunk-level software pipeline over 8 iterations ----
    uint4v gA_[NW], gB_[NW];
    short8 a0, a1;

    GATHER8(gA_, wA, lk8);      // prologue: iter0 chunk0

    ITER_FULL(A, B, 0);
    ITER_FULL(B, A, 1);
    ITER_FULL(A, B, 2);
    ITER_FULL(B, A, 3);
    ITER_FULL(A, B, 4);
    ITER_FULL(B, A, 5);
    ITER_NOLOAD(A, B, 6);
    ITER_LAST(B, 7);

#undef LOADT
#undef GATHER8
#undef SUMCVT
#undef MFST
#undef ITER_FULL
#undef ITER_NOLOAD
#undef ITER_LAST
}

extern "C" void kernel_launch(void* const* d_in, const int* in_sizes, int n_in,
                              void* d_out, int out_size, void* d_ws, size_t ws_size,
                              hipStream_t stream) {
    const int*   seqs  = (const int*)d_in[0];
    const int*   qtok  = (const int*)d_in[1];
    const float* embed = (const float*)d_in[2];
    const float* W1    = (const float*)d_in[3];
    const float* b1    = (const float*)d_in[4];
    const float* W2    = (const float*)d_in[5];
    const float* b2    = (const float*)d_in[6];
    float* out = (float*)d_out;
    unsigned short* tbl = (unsigned short*)d_ws;

    int B = in_sizes[0] / SEQ;

    build_tables<<<NTOK * 2, HID, 0, stream>>>(embed, W1, b1, tbl);

    int grid = B / (ITERS * ROWS_PER_ITER);
    fused_forward<<<grid, 256, 0, stream>>>(seqs, qtok, W2, b2, tbl, out);
}